// Round 5
// baseline (1635.698 us; speedup 1.0000x reference)
//
#include <hip/hip_runtime.h>
#include <hip/hip_fp16.h>
#include <math.h>

#define SD 10
#define BB 6                  // bucket bits (nodes-per-bucket = 64)
#define BSZ 64                // nodes per bucket
#define MAXNB 3328            // LDS hist capacity; N <= 3328*64 = 212992
#define EB 512                // edge-chunk blocks for passes A/C
#define CTHR 512              // threads for passes A/C

typedef unsigned uvec4 __attribute__((ext_vector_type(4)));
union U32H2 { unsigned u; __half2 h; };

__device__ __forceinline__ float tanh_fast(float x) {
    float e = __expf(2.0f * x);
    float r = __builtin_amdgcn_rcpf(1.0f + e);
    return 1.0f - 2.0f * r;
}

__device__ __forceinline__ float softplus_f(float x) {
    return fmaxf(x, 0.0f) + log1pf(expf(-fabsf(x)));
}

// ===================== prep =====================

__global__ __launch_bounds__(256) void coords4_kernel(
    const float* __restrict__ coords, float4* __restrict__ coords4, int N)
{
    int n = blockIdx.x * blockDim.x + threadIdx.x;
    if (n >= N) return;
    float4 c;
    c.x = coords[n * 3 + 0];
    c.y = coords[n * 3 + 1];
    c.z = coords[n * 3 + 2];
    c.w = 0.0f;
    coords4[n] = c;
}

// ===================== build: deterministic multi-split =====================

__global__ __launch_bounds__(CTHR) void bucket_count_kernel(
    const int* __restrict__ nto, unsigned* __restrict__ gcnt, int E, int NB)
{
    __shared__ unsigned h[MAXNB];
    int b = blockIdx.x;
    for (int i = threadIdx.x; i < NB; i += CTHR) h[i] = 0;
    __syncthreads();
    long long ebeg = (long long)E * b / EB;
    long long eend = (long long)E * (b + 1) / EB;
    for (long long e = ebeg + threadIdx.x; e < eend; e += CTHR)
        atomicAdd(&h[((unsigned)nto[e]) >> BB], 1u);
    __syncthreads();
    for (int k = threadIdx.x; k < NB; k += CTHR) gcnt[(size_t)k * EB + b] = h[k];
}

// Exclusive scan, level: 1024 items per 256-thread block. (no __restrict__: called in-place)
__global__ __launch_bounds__(256) void scan1_kernel(
    const unsigned* cnt, unsigned* off, unsigned* bsum, int M)
{
    __shared__ unsigned lds[256];
    int t = threadIdx.x, b = blockIdx.x;
    int base = b * 1024 + t * 4;
    unsigned v[4], s = 0;
#pragma unroll
    for (int k = 0; k < 4; k++) {
        v[k] = (base + k < M) ? cnt[base + k] : 0u;
        s += v[k];
    }
    lds[t] = s;
    __syncthreads();
    for (int d = 1; d < 256; d <<= 1) {
        unsigned x = (t >= d) ? lds[t - d] : 0u;
        __syncthreads();
        lds[t] += x;
        __syncthreads();
    }
    unsigned excl = (t > 0) ? lds[t - 1] : 0u;
    if (t == 255) bsum[b] = lds[255];
    unsigned run = excl;
#pragma unroll
    for (int k = 0; k < 4; k++) {
        if (base + k < M) off[base + k] = run;
        run += v[k];
    }
}

__global__ __launch_bounds__(256) void scan2_kernel(unsigned* __restrict__ bsum, int nb)
{
    __shared__ unsigned lds[256];
    int t = threadIdx.x;
    unsigned v = (t < nb) ? bsum[t] : 0u;
    lds[t] = v;
    __syncthreads();
    for (int d = 1; d < 256; d <<= 1) {
        unsigned x = (t >= d) ? lds[t - d] : 0u;
        __syncthreads();
        lds[t] += x;
        __syncthreads();
    }
    unsigned excl = (t > 0) ? lds[t - 1] : 0u;
    if (t < nb) bsum[t] = excl;
}

__global__ __launch_bounds__(256) void scan_add_kernel(
    unsigned* __restrict__ off, const unsigned* __restrict__ bsum, int M)
{
    int i = blockIdx.x * blockDim.x + threadIdx.x;
    if (i < M) off[i] += bsum[i >> 10];
}

__global__ __launch_bounds__(256) void bstart_kernel(
    const unsigned* __restrict__ gbase, unsigned* __restrict__ bstart, int NB, int E)
{
    int k = blockIdx.x * blockDim.x + threadIdx.x;
    if (k > NB) return;
    bstart[k] = (k < NB) ? gbase[(size_t)k * EB] : (unsigned)E;
}

// Pass C: emit bucket-sorted 16B payload {nf|lnt<<18, fp16 g0g1, fp16 g2g3, 0}
__global__ __launch_bounds__(CTHR) void bucket_scatter_kernel(
    const float4* __restrict__ coords4,
    const float* __restrict__ elen,
    const float* __restrict__ evec,
    const int* __restrict__ nfrom,
    const int* __restrict__ nto,
    const unsigned* __restrict__ gbase,
    uvec4* __restrict__ payload,
    int E, int NB)
{
    __shared__ unsigned cur[MAXNB];
    int b = blockIdx.x;
    for (int k = threadIdx.x; k < NB; k += CTHR) cur[k] = gbase[(size_t)k * EB + b];
    __syncthreads();
    long long ebeg = (long long)E * b / EB;
    long long eend = (long long)E * (b + 1) / EB;
    for (long long e = ebeg + threadIdx.x; e < eend; e += CTHR) {
        int nf = nfrom[e];
        int nt = nto[e];
        unsigned k = ((unsigned)nt) >> BB;
        unsigned pos = atomicAdd(&cur[k], 1u);

        float4 cf = coords4[nf];
        float4 ct = coords4[nt];
        float ev0 = evec[e * 3 + 0], ev1 = evec[e * 3 + 1], ev2 = evec[e * 3 + 2];

        float g0 = elen[e];
        float g1 = fabsf(cf.x) + fabsf(cf.y) + fabsf(cf.z);
        float g2 = cf.x * ct.x + cf.y * ct.y + cf.z * ct.z;
        float g3 = cf.x * ev0 + cf.y * ev1 + cf.z * ev2;

        U32H2 c01, c23;
        c01.h = __floats2half2_rn(g0, g1);
        c23.h = __floats2half2_rn(g2, g3);
        uvec4 p;
        p.x = (unsigned)nf | (((unsigned)nt & (BSZ - 1)) << 18);
        p.y = c01.u;
        p.z = c23.u;
        p.w = 0u;
        __builtin_nontemporal_store(p, &payload[pos]);
    }
}

// ===================== rounds =====================

// wsth[n][j] = fp16( bm[j] + sum_k state[n][k] * Wm[k][j] ), dense 20B rows (4MB total)
__global__ __launch_bounds__(256) void wstate_kernel(
    const float* __restrict__ state, const float* __restrict__ Wm,
    const float* __restrict__ bm, __half* __restrict__ wsth, int N)
{
    int n = blockIdx.x * blockDim.x + threadIdx.x;
    if (n >= N) return;
    const float2* sp = (const float2*)(state + (size_t)n * SD);
    float s[SD];
#pragma unroll
    for (int h = 0; h < 5; h++) { float2 v = sp[h]; s[2*h] = v.x; s[2*h+1] = v.y; }
    float t[SD];
#pragma unroll
    for (int j = 0; j < SD; j++) t[j] = bm[j];
#pragma unroll
    for (int k = 0; k < SD; k++) {
#pragma unroll
        for (int j = 0; j < SD; j++) t[j] += s[k] * Wm[k * SD + j];
    }
    unsigned* dp = (unsigned*)(wsth + (size_t)n * SD);   // 20B rows, 4B aligned
#pragma unroll
    for (int h = 0; h < 5; h++) {
        U32H2 cv;
        cv.h = __floats2half2_rn(t[2*h], t[2*h+1]);
        dp[h] = cv.u;
    }
}

// Wave-cooperative, 3-stage software pipeline: 10 lanes/edge, 6 edges/wave.
// iter i: issue payload[i+2]; issue wst[i+1] (payload a full iter old); compute edge i.
template <bool FIRST>
__global__ __launch_bounds__(256) void round_wave_kernel(
    const unsigned* __restrict__ bstart,
    const uvec4* __restrict__ payload,
    const float* __restrict__ Wm,
    const float* __restrict__ bm,
    const __half* __restrict__ wsth,      // (N,10) dense fp16, incl bias
    const float* __restrict__ state_prev,
    float* __restrict__ state_next,
    int N)
{
    __shared__ float acc[BSZ * SD];       // 2.56 KB
    int k = blockIdx.x;
    for (int i = threadIdx.x; i < BSZ * SD; i += 256) acc[i] = 0.0f;

    int lane = threadIdx.x & 63;
    int wv = threadIdx.x >> 6;            // 0..3
    int grp = lane / 10;                  // 0..5 (6 edges), lanes 60..63 idle
    int j = lane - grp * 10;              // 0..9
    bool active = (lane < 60);

    float w0 = Wm[10 * SD + j];
    float w1 = Wm[11 * SD + j];
    float w2 = Wm[12 * SD + j];
    float w3 = Wm[13 * SD + j];
    float bb = bm[j];
    __syncthreads();

    unsigned beg = bstart[k], end = bstart[k + 1];
    const unsigned STRIDE = 24;

    unsigned base = beg + wv * 6;
    // stage 0 preload
    bool v0 = active && (base + grp) < end;
    uvec4 p0 = {0,0,0,0};
    if (v0) p0 = __builtin_nontemporal_load(&payload[base + grp]);
    // stage 1 preload
    bool v1 = active && (base + STRIDE + grp) < end;
    uvec4 p1 = {0,0,0,0};
    if (v1) p1 = __builtin_nontemporal_load(&payload[base + STRIDE + grp]);
    // wst for stage 0
    float tw0 = 0.0f;
    if (!FIRST && v0) tw0 = __half2float(wsth[(size_t)(p0.x & 0x3FFFFu) * SD + j]);

    for (; base < end; ) {
        // issue payload i+2
        unsigned b2 = base + 2 * STRIDE;
        bool v2 = active && (b2 + grp) < end;
        uvec4 p2 = {0,0,0,0};
        if (v2) p2 = __builtin_nontemporal_load(&payload[b2 + grp]);
        // issue wst i+1 (p1 loaded a full iteration ago)
        float tw1 = 0.0f;
        if (!FIRST && v1) tw1 = __half2float(wsth[(size_t)(p1.x & 0x3FFFFu) * SD + j]);
        // compute edge i
        if (v0) {
            int lnt = (int)((p0.x >> 18) & (BSZ - 1));
            U32H2 c01, c23;
            c01.u = p0.y; c23.u = p0.z;
            float g0 = __low2float(c01.h), g1 = __high2float(c01.h);
            float g2 = __low2float(c23.h), g3 = __high2float(c23.h);
            float t = FIRST ? bb : tw0;
            t += g0 * w0 + g1 * w1 + g2 * w2 + g3 * w3;
            atomicAdd(&acc[lnt * SD + j], tanh_fast(t));
        }
        base += STRIDE;
        v0 = v1; p0 = p1; tw0 = tw1;
        v1 = v2; p1 = p2;
    }
    __syncthreads();

    int base_o = k * BSZ * SD;
    int lim = N * SD - base_o;
    for (int i = threadIdx.x; i < BSZ * SD; i += 256) {
        if (i < lim) {
            float v = acc[i];
            if (!FIRST) v += state_prev[base_o + i];
            state_next[base_o + i] = v;
        }
    }
}

// ===================== graph phase =====================

__global__ __launch_bounds__(256) void goff_kernel(
    const int* __restrict__ gidx, unsigned* __restrict__ goff, int N, int G)
{
    int n = blockIdx.x * blockDim.x + threadIdx.x;
    if (n >= N) return;
    int g = gidx[n];
    if (n == 0) {
        for (int q = 0; q <= g; q++) goff[q] = 0;
    } else {
        int gp = gidx[n - 1];
        for (int q = gp + 1; q <= g; q++) goff[q] = (unsigned)n;
    }
    if (n == N - 1) {
        for (int q = g + 1; q <= G; q++) goff[q] = (unsigned)N;
    }
}

// 4-way split per (g,j); one atomic per partial. gstate must be zeroed.
__global__ __launch_bounds__(256) void gsum_kernel(
    const float* __restrict__ state, const unsigned* __restrict__ goff,
    float* __restrict__ gstate, int G)
{
    int tid = blockIdx.x * blockDim.x + threadIdx.x;
    if (tid >= G * SD * 4) return;
    int s = tid & 3;
    int rest = tid >> 2;
    int g = rest / SD;
    int j = rest - g * SD;
    unsigned beg = goff[g], end = goff[g + 1];
    unsigned len = end - beg;
    unsigned b0 = beg + (len * (unsigned)s) / 4u;
    unsigned b1 = beg + (len * (unsigned)(s + 1)) / 4u;
    float a = 0.0f;
    for (unsigned n = b0; n < b1; n++) a += state[(size_t)n * SD + j];
    atomicAdd(&gstate[(size_t)g * SD + j], a);
}

__global__ __launch_bounds__(256) void out_kernel(
    const float* __restrict__ gstate, const float* __restrict__ Wo,
    const float* __restrict__ bo, float* __restrict__ out, int G)
{
    int g = blockIdx.x * blockDim.x + threadIdx.x;
    if (g >= G) return;
    float s[SD];
#pragma unroll
    for (int k = 0; k < SD; k++) s[k] = gstate[(size_t)g * SD + k];
    float ev[4];
#pragma unroll
    for (int c = 0; c < 4; c++) {
        float a = bo[c];
#pragma unroll
        for (int k = 0; k < SD; k++) a += s[k] * Wo[k * 4 + c];
        ev[c] = a;
    }
    out[g * 4 + 0] = ev[0];
    out[g * 4 + 1] = softplus_f(ev[1]);
    out[g * 4 + 2] = softplus_f(ev[2]) + 1.0f;
    out[g * 4 + 3] = softplus_f(ev[3]);
}

// ===================== fallback (atomic path) =====================

template <bool FIRST>
__global__ __launch_bounds__(256) void edge_kernel_fb(
    const float* __restrict__ coords, const float* __restrict__ elen,
    const float* __restrict__ evec, const float* __restrict__ Wm,
    const float* __restrict__ bm, const int* __restrict__ nfrom,
    const int* __restrict__ nto, const float* __restrict__ state_prev,
    float* __restrict__ state_next, int E)
{
    int e = blockIdx.x * blockDim.x + threadIdx.x;
    if (e >= E) return;
    int nf = nfrom[e];
    int nt = nto[e];
    float cf0 = coords[nf*3+0], cf1 = coords[nf*3+1], cf2 = coords[nf*3+2];
    float ct0 = coords[nt*3+0], ct1 = coords[nt*3+1], ct2 = coords[nt*3+2];
    float ev0 = evec[e*3+0], ev1 = evec[e*3+1], ev2 = evec[e*3+2];
    float g0 = elen[e];
    float g1 = fabsf(cf0) + fabsf(cf1) + fabsf(cf2);
    float g2 = cf0*ct0 + cf1*ct1 + cf2*ct2;
    float g3 = cf0*ev0 + cf1*ev1 + cf2*ev2;
    float acc[SD];
#pragma unroll
    for (int j = 0; j < SD; j++) {
        acc[j] = bm[j] + g0*Wm[10*SD+j] + g1*Wm[11*SD+j] + g2*Wm[12*SD+j] + g3*Wm[13*SD+j];
    }
    if (!FIRST) {
        const float2* sp = (const float2*)(state_prev + (size_t)nf * SD);
        float s[SD];
#pragma unroll
        for (int h = 0; h < 5; h++) { float2 v = sp[h]; s[2*h] = v.x; s[2*h+1] = v.y; }
#pragma unroll
        for (int k = 0; k < SD; k++) {
#pragma unroll
            for (int j = 0; j < SD; j++) acc[j] += s[k] * Wm[k*SD+j];
        }
    }
    float* dst = state_next + (size_t)nt * SD;
#pragma unroll
    for (int j = 0; j < SD; j++) atomicAdd(dst + j, tanh_fast(acc[j]));
}

__global__ __launch_bounds__(256) void graph_reduce_fb(
    const float* __restrict__ state, const int* __restrict__ gidx,
    float* __restrict__ gstate, int N)
{
    int n = blockIdx.x * blockDim.x + threadIdx.x;
    if (n >= N) return;
    int g = gidx[n];
    const float2* sp = (const float2*)(state + (size_t)n * SD);
    float* dst = gstate + (size_t)g * SD;
#pragma unroll
    for (int h = 0; h < 5; h++) {
        float2 v = sp[h];
        atomicAdd(dst + 2*h, v.x);
        atomicAdd(dst + 2*h + 1, v.y);
    }
}

// ===================== launch =====================

extern "C" void kernel_launch(void* const* d_in, const int* in_sizes, int n_in,
                              void* d_out, int out_size, void* d_ws, size_t ws_size,
                              hipStream_t stream) {
    const float* coords = (const float*)d_in[0];
    const float* elen   = (const float*)d_in[1];
    const float* evec   = (const float*)d_in[2];
    const float* Wm     = (const float*)d_in[3];
    const float* bm     = (const float*)d_in[4];
    const float* Wo     = (const float*)d_in[5];
    const float* bo     = (const float*)d_in[6];
    const int* nfrom    = (const int*)d_in[7];
    const int* nto      = (const int*)d_in[8];
    const int* gidx     = (const int*)d_in[9];

    const int E = in_sizes[1];
    const int N = in_sizes[9];
    const int G = out_size / 4;

    const int NB  = (N + BSZ - 1) / BSZ;     // buckets
    const int M   = NB * EB;                 // scan length
    const int nb1 = (M + 1023) / 1024;       // scan level-1 blocks
    const int nb2 = (nb1 + 1023) / 1024;     // scan level-2 blocks

    const int BLK = 256;
    const int ng = (N + BLK - 1) / BLK;
    const int gg = (G + BLK - 1) / BLK;

    auto align256 = [](size_t x) { return (x + 255) & ~(size_t)255; };
    const size_t state_bytes = align256((size_t)N * SD * sizeof(float));
    const size_t wst_bytes   = align256((size_t)N * SD * sizeof(__half));
    const size_t pay_bytes   = align256((size_t)E * sizeof(uvec4));
    const size_t gcnt_bytes  = align256((size_t)M * sizeof(unsigned));
    const size_t bsumA_bytes = align256((size_t)nb1 * sizeof(unsigned));
    const size_t bsumB_bytes = align256((size_t)(nb2 > 0 ? nb2 : 1) * sizeof(unsigned) + 256);
    const size_t bst_bytes   = align256((size_t)(NB + 1) * sizeof(unsigned));
    const size_t goff_bytes  = align256((size_t)(G + 1) * sizeof(unsigned));
    const size_t gst_bytes   = align256((size_t)G * SD * sizeof(float));
    const size_t c4_bytes    = align256((size_t)N * sizeof(float4));

    size_t o = 0;
    char* w = (char*)d_ws;
    float* stateA    = (float*)(w + o);    o += state_bytes;
    float* stateB    = (float*)(w + o);    o += state_bytes;
    __half* wsth     = (__half*)(w + o);   o += wst_bytes;
    uvec4* payload   = (uvec4*)(w + o);    o += pay_bytes;
    unsigned* gcnt   = (unsigned*)(w + o); o += gcnt_bytes;
    unsigned* gbase  = (unsigned*)(w + o); o += gcnt_bytes;
    unsigned* bsumA  = (unsigned*)(w + o); o += bsumA_bytes;
    unsigned* bsumB  = (unsigned*)(w + o); o += bsumB_bytes;
    unsigned* bstart = (unsigned*)(w + o); o += bst_bytes;
    unsigned* goff   = (unsigned*)(w + o); o += goff_bytes;
    float* gstate    = (float*)(w + o);    o += gst_bytes;
    float4* coords4  = (float4*)(w + o);   o += c4_bytes;

    if (o <= ws_size && NB <= MAXNB && nb1 <= 1024 * 256 && nb2 <= 256 && N < (1 << 18)) {
        // ---- prep + build (no global atomics) ----
        coords4_kernel<<<ng, BLK, 0, stream>>>(coords, coords4, N);
        bucket_count_kernel<<<EB, CTHR, 0, stream>>>(nto, gcnt, E, NB);
        scan1_kernel<<<nb1, 256, 0, stream>>>(gcnt, gbase, bsumA, M);
        scan1_kernel<<<nb2, 256, 0, stream>>>(bsumA, bsumA, bsumB, nb1);   // in-place OK
        scan2_kernel<<<1, 256, 0, stream>>>(bsumB, nb2);
        scan_add_kernel<<<(nb1 + 255) / 256, 256, 0, stream>>>(bsumA, bsumB, nb1);
        scan_add_kernel<<<(M + 255) / 256, 256, 0, stream>>>(gbase, bsumA, M);
        bstart_kernel<<<(NB + 256) / 256, 256, 0, stream>>>(gbase, bstart, NB, E);
        bucket_scatter_kernel<<<EB, CTHR, 0, stream>>>(coords4, elen, evec, nfrom, nto,
                                                       gbase, payload, E, NB);
        // ---- rounds ----
        round_wave_kernel<true><<<NB, BLK, 0, stream>>>(bstart, payload, Wm, bm,
                                                        wsth, stateB, stateA, N);
        wstate_kernel<<<ng, BLK, 0, stream>>>(stateA, Wm, bm, wsth, N);
        round_wave_kernel<false><<<NB, BLK, 0, stream>>>(bstart, payload, Wm, bm,
                                                         wsth, stateA, stateB, N);
        wstate_kernel<<<ng, BLK, 0, stream>>>(stateB, Wm, bm, wsth, N);
        round_wave_kernel<false><<<NB, BLK, 0, stream>>>(bstart, payload, Wm, bm,
                                                         wsth, stateB, stateA, N);
        // ---- graph phase ----
        hipMemsetAsync(gstate, 0, (size_t)G * SD * sizeof(float), stream);
        goff_kernel<<<ng, BLK, 0, stream>>>(gidx, goff, N, G);
        gsum_kernel<<<(G * SD * 4 + BLK - 1) / BLK, BLK, 0, stream>>>(stateA, goff, gstate, G);
        out_kernel<<<gg, BLK, 0, stream>>>(gstate, Wo, bo, (float*)d_out, G);
    } else {
        // ---- fallback: atomic path ----
        const int eg = (E + BLK - 1) / BLK;
        float* gstateF = (float*)(w + 2 * state_bytes);
        hipMemsetAsync(stateA, 0, state_bytes, stream);
        hipMemsetAsync(gstateF, 0, (size_t)G * SD * sizeof(float), stream);
        edge_kernel_fb<true><<<eg, BLK, 0, stream>>>(coords, elen, evec, Wm, bm,
                                                     nfrom, nto, stateA, stateA, E);
        hipMemcpyAsync(stateB, stateA, state_bytes, hipMemcpyDeviceToDevice, stream);
        edge_kernel_fb<false><<<eg, BLK, 0, stream>>>(coords, elen, evec, Wm, bm,
                                                      nfrom, nto, stateA, stateB, E);
        hipMemcpyAsync(stateA, stateB, state_bytes, hipMemcpyDeviceToDevice, stream);
        edge_kernel_fb<false><<<eg, BLK, 0, stream>>>(coords, elen, evec, Wm, bm,
                                                      nfrom, nto, stateB, stateA, E);
        graph_reduce_fb<<<ng, BLK, 0, stream>>>(stateA, gidx, gstateF, N);
        out_kernel<<<gg, BLK, 0, stream>>>(gstateF, Wo, bo, (float*)d_out, G);
    }
}

// Round 6
// 1605.799 us; speedup vs baseline: 1.0186x; 1.0186x over previous
//
#include <hip/hip_runtime.h>
#include <hip/hip_fp16.h>
#include <math.h>

#define SD 10
#define BB 6                  // bucket bits (nodes-per-bucket = 64)
#define BSZ 64                // nodes per bucket
#define MAXNB 3328            // LDS hist capacity; N <= 3328*64 = 212992
#define EB 512                // edge-chunk blocks for passes A/C
#define CTHR 512              // threads for passes A/C

typedef unsigned uvec4 __attribute__((ext_vector_type(4)));
union U32H2 { unsigned u; __half2 h; };

__device__ __forceinline__ float tanh_fast(float x) {
    float e = __expf(2.0f * x);
    float r = __builtin_amdgcn_rcpf(1.0f + e);
    return 1.0f - 2.0f * r;
}

__device__ __forceinline__ float softplus_f(float x) {
    return fmaxf(x, 0.0f) + log1pf(expf(-fabsf(x)));
}

// ===================== prep =====================

__global__ __launch_bounds__(256) void coords4_kernel(
    const float* __restrict__ coords, float4* __restrict__ coords4, int N)
{
    int n = blockIdx.x * blockDim.x + threadIdx.x;
    if (n >= N) return;
    float4 c;
    c.x = coords[n * 3 + 0];
    c.y = coords[n * 3 + 1];
    c.z = coords[n * 3 + 2];
    c.w = 0.0f;
    coords4[n] = c;
}

// ===================== build: deterministic multi-split =====================

__global__ __launch_bounds__(CTHR) void bucket_count_kernel(
    const int* __restrict__ nto, unsigned* __restrict__ gcnt, int E, int NB)
{
    __shared__ unsigned h[MAXNB];
    int b = blockIdx.x;
    for (int i = threadIdx.x; i < NB; i += CTHR) h[i] = 0;
    __syncthreads();
    long long ebeg = (long long)E * b / EB;
    long long eend = (long long)E * (b + 1) / EB;
    for (long long e = ebeg + threadIdx.x; e < eend; e += CTHR)
        atomicAdd(&h[((unsigned)nto[e]) >> BB], 1u);
    __syncthreads();
    for (int k = threadIdx.x; k < NB; k += CTHR) gcnt[(size_t)k * EB + b] = h[k];
}

// Exclusive scan, level: 1024 items per 256-thread block. (no __restrict__: called in-place)
__global__ __launch_bounds__(256) void scan1_kernel(
    const unsigned* cnt, unsigned* off, unsigned* bsum, int M)
{
    __shared__ unsigned lds[256];
    int t = threadIdx.x, b = blockIdx.x;
    int base = b * 1024 + t * 4;
    unsigned v[4], s = 0;
#pragma unroll
    for (int k = 0; k < 4; k++) {
        v[k] = (base + k < M) ? cnt[base + k] : 0u;
        s += v[k];
    }
    lds[t] = s;
    __syncthreads();
    for (int d = 1; d < 256; d <<= 1) {
        unsigned x = (t >= d) ? lds[t - d] : 0u;
        __syncthreads();
        lds[t] += x;
        __syncthreads();
    }
    unsigned excl = (t > 0) ? lds[t - 1] : 0u;
    if (t == 255) bsum[b] = lds[255];
    unsigned run = excl;
#pragma unroll
    for (int k = 0; k < 4; k++) {
        if (base + k < M) off[base + k] = run;
        run += v[k];
    }
}

__global__ __launch_bounds__(256) void scan2_kernel(unsigned* __restrict__ bsum, int nb)
{
    __shared__ unsigned lds[256];
    int t = threadIdx.x;
    unsigned v = (t < nb) ? bsum[t] : 0u;
    lds[t] = v;
    __syncthreads();
    for (int d = 1; d < 256; d <<= 1) {
        unsigned x = (t >= d) ? lds[t - d] : 0u;
        __syncthreads();
        lds[t] += x;
        __syncthreads();
    }
    unsigned excl = (t > 0) ? lds[t - 1] : 0u;
    if (t < nb) bsum[t] = excl;
}

__global__ __launch_bounds__(256) void scan_add_kernel(
    unsigned* __restrict__ off, const unsigned* __restrict__ bsum, int M)
{
    int i = blockIdx.x * blockDim.x + threadIdx.x;
    if (i < M) off[i] += bsum[i >> 10];
}

__global__ __launch_bounds__(256) void bstart_kernel(
    const unsigned* __restrict__ gbase, unsigned* __restrict__ bstart, int NB, int E)
{
    int k = blockIdx.x * blockDim.x + threadIdx.x;
    if (k > NB) return;
    bstart[k] = (k < NB) ? gbase[(size_t)k * EB] : (unsigned)E;
}

// Pass C: emit bucket-sorted 16B payload {nf|lnt<<18, fp16 g0g1, fp16 g2g3, 0}
__global__ __launch_bounds__(CTHR) void bucket_scatter_kernel(
    const float4* __restrict__ coords4,
    const float* __restrict__ elen,
    const float* __restrict__ evec,
    const int* __restrict__ nfrom,
    const int* __restrict__ nto,
    const unsigned* __restrict__ gbase,
    uvec4* __restrict__ payload,
    int E, int NB)
{
    __shared__ unsigned cur[MAXNB];
    int b = blockIdx.x;
    for (int k = threadIdx.x; k < NB; k += CTHR) cur[k] = gbase[(size_t)k * EB + b];
    __syncthreads();
    long long ebeg = (long long)E * b / EB;
    long long eend = (long long)E * (b + 1) / EB;
    for (long long e = ebeg + threadIdx.x; e < eend; e += CTHR) {
        int nf = nfrom[e];
        int nt = nto[e];
        unsigned k = ((unsigned)nt) >> BB;
        unsigned pos = atomicAdd(&cur[k], 1u);

        float4 cf = coords4[nf];
        float4 ct = coords4[nt];
        float ev0 = evec[e * 3 + 0], ev1 = evec[e * 3 + 1], ev2 = evec[e * 3 + 2];

        float g0 = elen[e];
        float g1 = fabsf(cf.x) + fabsf(cf.y) + fabsf(cf.z);
        float g2 = cf.x * ct.x + cf.y * ct.y + cf.z * ct.z;
        float g3 = cf.x * ev0 + cf.y * ev1 + cf.z * ev2;

        U32H2 c01, c23;
        c01.h = __floats2half2_rn(g0, g1);
        c23.h = __floats2half2_rn(g2, g3);
        uvec4 p;
        p.x = (unsigned)nf | (((unsigned)nt & (BSZ - 1)) << 18);
        p.y = c01.u;
        p.z = c23.u;
        p.w = 0u;
        __builtin_nontemporal_store(p, &payload[pos]);
    }
}

// ===================== rounds =====================

// wsth[n][j] = fp16( bm[j] + sum_k state[n][k] * Wm[k][j] ), dense 20B rows (4MB total)
__global__ __launch_bounds__(256) void wstate_kernel(
    const float* __restrict__ state, const float* __restrict__ Wm,
    const float* __restrict__ bm, __half* __restrict__ wsth, int N)
{
    int n = blockIdx.x * blockDim.x + threadIdx.x;
    if (n >= N) return;
    const float2* sp = (const float2*)(state + (size_t)n * SD);
    float s[SD];
#pragma unroll
    for (int h = 0; h < 5; h++) { float2 v = sp[h]; s[2*h] = v.x; s[2*h+1] = v.y; }
    float t[SD];
#pragma unroll
    for (int j = 0; j < SD; j++) t[j] = bm[j];
#pragma unroll
    for (int k = 0; k < SD; k++) {
#pragma unroll
        for (int j = 0; j < SD; j++) t[j] += s[k] * Wm[k * SD + j];
    }
    unsigned* dp = (unsigned*)(wsth + (size_t)n * SD);   // 20B rows, 4B aligned
#pragma unroll
    for (int h = 0; h < 5; h++) {
        U32H2 cv;
        cv.h = __floats2half2_rn(t[2*h], t[2*h+1]);
        dp[h] = cv.u;
    }
}

// Wave-cooperative, 10 lanes/edge, UNROLL=4 (24 edges/wave/iter), payload prefetch
// depth 3, wst prefetch depth 1. wst loads are issued FIRST in the body so the
// compute-side vmcnt wait (in-order) never drags in the young payload loads.
#define UNR 4
template <bool FIRST>
__global__ __launch_bounds__(256, 4) void round_wave_kernel(
    const unsigned* __restrict__ bstart,
    const uvec4* __restrict__ payload,
    const float* __restrict__ Wm,
    const float* __restrict__ bm,
    const __half* __restrict__ wsth,      // (N,10) dense fp16, incl bias
    const float* __restrict__ state_prev,
    float* __restrict__ state_next,
    int N, int E)
{
    __shared__ float acc[BSZ * SD];       // 2.56 KB
    int k = blockIdx.x;
    for (int i = threadIdx.x; i < BSZ * SD; i += 256) acc[i] = 0.0f;

    int lane = threadIdx.x & 63;
    int wv = threadIdx.x >> 6;            // 0..3
    int grp0 = lane / 10;
    bool active = grp0 < 6;
    int grp = active ? grp0 : 5;          // lanes 60..63 mirror group 5 (dup loads, no extra lines)
    int j = active ? (lane - grp0 * 10) : (lane - 60);  // inactive: j=0..3, mirrors grp5 lanes

    float w0 = Wm[10 * SD + j];
    float w1 = Wm[11 * SD + j];
    float w2 = Wm[12 * SD + j];
    float w3 = Wm[13 * SD + j];
    float bb = bm[j];
    __syncthreads();

    unsigned beg = bstart[k], end = bstart[k + 1];
    const unsigned WSTEP = 4 * 6 * UNR;   // 96 edges per block-iter
    unsigned base = beg + (unsigned)wv * (6 * UNR);
    unsigned eclamp = (unsigned)E - 1u;

    uvec4 P0[UNR], P1[UNR], P2[UNR];
    float T0[UNR];

    // preload: payload stages 0..2, wst stage 0
#pragma unroll
    for (int u = 0; u < UNR; u++) {
        unsigned e = base + 6 * u + (unsigned)grp;
        P0[u] = __builtin_nontemporal_load(&payload[e <= eclamp ? e : eclamp]);
    }
#pragma unroll
    for (int u = 0; u < UNR; u++) {
        unsigned e = base + WSTEP + 6 * u + (unsigned)grp;
        P1[u] = __builtin_nontemporal_load(&payload[e <= eclamp ? e : eclamp]);
    }
#pragma unroll
    for (int u = 0; u < UNR; u++) {
        unsigned e = base + 2 * WSTEP + 6 * u + (unsigned)grp;
        P2[u] = __builtin_nontemporal_load(&payload[e <= eclamp ? e : eclamp]);
    }
    if (!FIRST) {
#pragma unroll
        for (int u = 0; u < UNR; u++)
            T0[u] = __half2float(wsth[(size_t)(P0[u].x & 0x3FFFFu) * SD + j]);
    } else {
#pragma unroll
        for (int u = 0; u < UNR; u++) T0[u] = bb;
    }

    for (; base < end; base += WSTEP) {
        // 1) wst for next iter, from P1 (payload issued 2 iters ago -> data ready)
        float T1[UNR];
        if (!FIRST) {
#pragma unroll
            for (int u = 0; u < UNR; u++)
                T1[u] = __half2float(wsth[(size_t)(P1[u].x & 0x3FFFFu) * SD + j]);
        } else {
#pragma unroll
            for (int u = 0; u < UNR; u++) T1[u] = bb;
        }
        // 2) payload 3 iters ahead (stays in flight across >=2 iterations)
        uvec4 Pn[UNR];
#pragma unroll
        for (int u = 0; u < UNR; u++) {
            unsigned e = base + 3 * WSTEP + 6 * u + (unsigned)grp;
            Pn[u] = __builtin_nontemporal_load(&payload[e <= eclamp ? e : eclamp]);
        }
        // 3) compute current iter from P0/T0 (both at least 1 iter old)
#pragma unroll
        for (int u = 0; u < UNR; u++) {
            unsigned e = base + 6 * u + (unsigned)grp;
            if (active && e < end) {
                int lnt = (int)((P0[u].x >> 18) & (BSZ - 1));
                U32H2 c01, c23;
                c01.u = P0[u].y; c23.u = P0[u].z;
                float g0 = __low2float(c01.h), g1 = __high2float(c01.h);
                float g2 = __low2float(c23.h), g3 = __high2float(c23.h);
                float t = T0[u] + g0 * w0 + g1 * w1 + g2 * w2 + g3 * w3;
                atomicAdd(&acc[lnt * SD + j], tanh_fast(t));
            }
        }
        // 4) shift pipeline
#pragma unroll
        for (int u = 0; u < UNR; u++) {
            P0[u] = P1[u]; P1[u] = P2[u]; P2[u] = Pn[u]; T0[u] = T1[u];
        }
    }
    __syncthreads();

    int base_o = k * BSZ * SD;
    int lim = N * SD - base_o;
    for (int i = threadIdx.x; i < BSZ * SD; i += 256) {
        if (i < lim) {
            float v = acc[i];
            if (!FIRST) v += state_prev[base_o + i];
            state_next[base_o + i] = v;
        }
    }
}

// ===================== graph phase =====================

__global__ __launch_bounds__(256) void goff_kernel(
    const int* __restrict__ gidx, unsigned* __restrict__ goff, int N, int G)
{
    int n = blockIdx.x * blockDim.x + threadIdx.x;
    if (n >= N) return;
    int g = gidx[n];
    if (n == 0) {
        for (int q = 0; q <= g; q++) goff[q] = 0;
    } else {
        int gp = gidx[n - 1];
        for (int q = gp + 1; q <= g; q++) goff[q] = (unsigned)n;
    }
    if (n == N - 1) {
        for (int q = g + 1; q <= G; q++) goff[q] = (unsigned)N;
    }
}

// 4-way split per (g,j); one atomic per partial. gstate must be zeroed.
__global__ __launch_bounds__(256) void gsum_kernel(
    const float* __restrict__ state, const unsigned* __restrict__ goff,
    float* __restrict__ gstate, int G)
{
    int tid = blockIdx.x * blockDim.x + threadIdx.x;
    if (tid >= G * SD * 4) return;
    int s = tid & 3;
    int rest = tid >> 2;
    int g = rest / SD;
    int j = rest - g * SD;
    unsigned beg = goff[g], end = goff[g + 1];
    unsigned len = end - beg;
    unsigned b0 = beg + (len * (unsigned)s) / 4u;
    unsigned b1 = beg + (len * (unsigned)(s + 1)) / 4u;
    float a = 0.0f;
    for (unsigned n = b0; n < b1; n++) a += state[(size_t)n * SD + j];
    atomicAdd(&gstate[(size_t)g * SD + j], a);
}

__global__ __launch_bounds__(256) void out_kernel(
    const float* __restrict__ gstate, const float* __restrict__ Wo,
    const float* __restrict__ bo, float* __restrict__ out, int G)
{
    int g = blockIdx.x * blockDim.x + threadIdx.x;
    if (g >= G) return;
    float s[SD];
#pragma unroll
    for (int k = 0; k < SD; k++) s[k] = gstate[(size_t)g * SD + k];
    float ev[4];
#pragma unroll
    for (int c = 0; c < 4; c++) {
        float a = bo[c];
#pragma unroll
        for (int k = 0; k < SD; k++) a += s[k] * Wo[k * 4 + c];
        ev[c] = a;
    }
    out[g * 4 + 0] = ev[0];
    out[g * 4 + 1] = softplus_f(ev[1]);
    out[g * 4 + 2] = softplus_f(ev[2]) + 1.0f;
    out[g * 4 + 3] = softplus_f(ev[3]);
}

// ===================== fallback (atomic path) =====================

template <bool FIRST>
__global__ __launch_bounds__(256) void edge_kernel_fb(
    const float* __restrict__ coords, const float* __restrict__ elen,
    const float* __restrict__ evec, const float* __restrict__ Wm,
    const float* __restrict__ bm, const int* __restrict__ nfrom,
    const int* __restrict__ nto, const float* __restrict__ state_prev,
    float* __restrict__ state_next, int E)
{
    int e = blockIdx.x * blockDim.x + threadIdx.x;
    if (e >= E) return;
    int nf = nfrom[e];
    int nt = nto[e];
    float cf0 = coords[nf*3+0], cf1 = coords[nf*3+1], cf2 = coords[nf*3+2];
    float ct0 = coords[nt*3+0], ct1 = coords[nt*3+1], ct2 = coords[nt*3+2];
    float ev0 = evec[e*3+0], ev1 = evec[e*3+1], ev2 = evec[e*3+2];
    float g0 = elen[e];
    float g1 = fabsf(cf0) + fabsf(cf1) + fabsf(cf2);
    float g2 = cf0*ct0 + cf1*ct1 + cf2*ct2;
    float g3 = cf0*ev0 + cf1*ev1 + cf2*ev2;
    float acc[SD];
#pragma unroll
    for (int j = 0; j < SD; j++) {
        acc[j] = bm[j] + g0*Wm[10*SD+j] + g1*Wm[11*SD+j] + g2*Wm[12*SD+j] + g3*Wm[13*SD+j];
    }
    if (!FIRST) {
        const float2* sp = (const float2*)(state_prev + (size_t)nf * SD);
        float s[SD];
#pragma unroll
        for (int h = 0; h < 5; h++) { float2 v = sp[h]; s[2*h] = v.x; s[2*h+1] = v.y; }
#pragma unroll
        for (int k = 0; k < SD; k++) {
#pragma unroll
            for (int j = 0; j < SD; j++) acc[j] += s[k] * Wm[k*SD+j];
        }
    }
    float* dst = state_next + (size_t)nt * SD;
#pragma unroll
    for (int j = 0; j < SD; j++) atomicAdd(dst + j, tanh_fast(acc[j]));
}

__global__ __launch_bounds__(256) void graph_reduce_fb(
    const float* __restrict__ state, const int* __restrict__ gidx,
    float* __restrict__ gstate, int N)
{
    int n = blockIdx.x * blockDim.x + threadIdx.x;
    if (n >= N) return;
    int g = gidx[n];
    const float2* sp = (const float2*)(state + (size_t)n * SD);
    float* dst = gstate + (size_t)g * SD;
#pragma unroll
    for (int h = 0; h < 5; h++) {
        float2 v = sp[h];
        atomicAdd(dst + 2*h, v.x);
        atomicAdd(dst + 2*h + 1, v.y);
    }
}

// ===================== launch =====================

extern "C" void kernel_launch(void* const* d_in, const int* in_sizes, int n_in,
                              void* d_out, int out_size, void* d_ws, size_t ws_size,
                              hipStream_t stream) {
    const float* coords = (const float*)d_in[0];
    const float* elen   = (const float*)d_in[1];
    const float* evec   = (const float*)d_in[2];
    const float* Wm     = (const float*)d_in[3];
    const float* bm     = (const float*)d_in[4];
    const float* Wo     = (const float*)d_in[5];
    const float* bo     = (const float*)d_in[6];
    const int* nfrom    = (const int*)d_in[7];
    const int* nto      = (const int*)d_in[8];
    const int* gidx     = (const int*)d_in[9];

    const int E = in_sizes[1];
    const int N = in_sizes[9];
    const int G = out_size / 4;

    const int NB  = (N + BSZ - 1) / BSZ;     // buckets
    const int M   = NB * EB;                 // scan length
    const int nb1 = (M + 1023) / 1024;       // scan level-1 blocks
    const int nb2 = (nb1 + 1023) / 1024;     // scan level-2 blocks

    const int BLK = 256;
    const int ng = (N + BLK - 1) / BLK;
    const int gg = (G + BLK - 1) / BLK;

    auto align256 = [](size_t x) { return (x + 255) & ~(size_t)255; };
    const size_t state_bytes = align256((size_t)N * SD * sizeof(float));
    const size_t wst_bytes   = align256((size_t)N * SD * sizeof(__half) + 256);
    const size_t pay_bytes   = align256((size_t)E * sizeof(uvec4));
    const size_t gcnt_bytes  = align256((size_t)M * sizeof(unsigned));
    const size_t bsumA_bytes = align256((size_t)nb1 * sizeof(unsigned));
    const size_t bsumB_bytes = align256((size_t)(nb2 > 0 ? nb2 : 1) * sizeof(unsigned) + 256);
    const size_t bst_bytes   = align256((size_t)(NB + 1) * sizeof(unsigned));
    const size_t goff_bytes  = align256((size_t)(G + 1) * sizeof(unsigned));
    const size_t gst_bytes   = align256((size_t)G * SD * sizeof(float));
    const size_t c4_bytes    = align256((size_t)N * sizeof(float4));

    size_t o = 0;
    char* w = (char*)d_ws;
    float* stateA    = (float*)(w + o);    o += state_bytes;
    float* stateB    = (float*)(w + o);    o += state_bytes;
    __half* wsth     = (__half*)(w + o);   o += wst_bytes;
    uvec4* payload   = (uvec4*)(w + o);    o += pay_bytes;
    unsigned* gcnt   = (unsigned*)(w + o); o += gcnt_bytes;
    unsigned* gbase  = (unsigned*)(w + o); o += gcnt_bytes;
    unsigned* bsumA  = (unsigned*)(w + o); o += bsumA_bytes;
    unsigned* bsumB  = (unsigned*)(w + o); o += bsumB_bytes;
    unsigned* bstart = (unsigned*)(w + o); o += bst_bytes;
    unsigned* goff   = (unsigned*)(w + o); o += goff_bytes;
    float* gstate    = (float*)(w + o);    o += gst_bytes;
    float4* coords4  = (float4*)(w + o);   o += c4_bytes;

    if (o <= ws_size && NB <= MAXNB && nb1 <= 1024 * 256 && nb2 <= 256 && N < (1 << 18)) {
        // ---- prep + build (no global atomics) ----
        coords4_kernel<<<ng, BLK, 0, stream>>>(coords, coords4, N);
        bucket_count_kernel<<<EB, CTHR, 0, stream>>>(nto, gcnt, E, NB);
        scan1_kernel<<<nb1, 256, 0, stream>>>(gcnt, gbase, bsumA, M);
        scan1_kernel<<<nb2, 256, 0, stream>>>(bsumA, bsumA, bsumB, nb1);   // in-place OK
        scan2_kernel<<<1, 256, 0, stream>>>(bsumB, nb2);
        scan_add_kernel<<<(nb1 + 255) / 256, 256, 0, stream>>>(bsumA, bsumB, nb1);
        scan_add_kernel<<<(M + 255) / 256, 256, 0, stream>>>(gbase, bsumA, M);
        bstart_kernel<<<(NB + 256) / 256, 256, 0, stream>>>(gbase, bstart, NB, E);
        bucket_scatter_kernel<<<EB, CTHR, 0, stream>>>(coords4, elen, evec, nfrom, nto,
                                                       gbase, payload, E, NB);
        // ---- rounds ----
        round_wave_kernel<true><<<NB, BLK, 0, stream>>>(bstart, payload, Wm, bm,
                                                        wsth, stateB, stateA, N, E);
        wstate_kernel<<<ng, BLK, 0, stream>>>(stateA, Wm, bm, wsth, N);
        round_wave_kernel<false><<<NB, BLK, 0, stream>>>(bstart, payload, Wm, bm,
                                                         wsth, stateA, stateB, N, E);
        wstate_kernel<<<ng, BLK, 0, stream>>>(stateB, Wm, bm, wsth, N);
        round_wave_kernel<false><<<NB, BLK, 0, stream>>>(bstart, payload, Wm, bm,
                                                         wsth, stateB, stateA, N, E);
        // ---- graph phase ----
        hipMemsetAsync(gstate, 0, (size_t)G * SD * sizeof(float), stream);
        goff_kernel<<<ng, BLK, 0, stream>>>(gidx, goff, N, G);
        gsum_kernel<<<(G * SD * 4 + BLK - 1) / BLK, BLK, 0, stream>>>(stateA, goff, gstate, G);
        out_kernel<<<gg, BLK, 0, stream>>>(gstate, Wo, bo, (float*)d_out, G);
    } else {
        // ---- fallback: atomic path ----
        const int eg = (E + BLK - 1) / BLK;
        float* gstateF = (float*)(w + 2 * state_bytes);
        hipMemsetAsync(stateA, 0, state_bytes, stream);
        hipMemsetAsync(gstateF, 0, (size_t)G * SD * sizeof(float), stream);
        edge_kernel_fb<true><<<eg, BLK, 0, stream>>>(coords, elen, evec, Wm, bm,
                                                     nfrom, nto, stateA, stateA, E);
        hipMemcpyAsync(stateB, stateA, state_bytes, hipMemcpyDeviceToDevice, stream);
        edge_kernel_fb<false><<<eg, BLK, 0, stream>>>(coords, elen, evec, Wm, bm,
                                                      nfrom, nto, stateA, stateB, E);
        hipMemcpyAsync(stateA, stateB, state_bytes, hipMemcpyDeviceToDevice, stream);
        edge_kernel_fb<false><<<eg, BLK, 0, stream>>>(coords, elen, evec, Wm, bm,
                                                      nfrom, nto, stateB, stateA, E);
        graph_reduce_fb<<<ng, BLK, 0, stream>>>(stateA, gidx, gstateF, N);
        out_kernel<<<gg, BLK, 0, stream>>>(gstateF, Wo, bo, (float*)d_out, G);
    }
}

// Round 7
// 925.281 us; speedup vs baseline: 1.7678x; 1.7355x over previous
//
#include <hip/hip_runtime.h>
#include <hip/hip_fp16.h>
#include <math.h>

#define SD 10
#define BB 6                  // bucket bits (nodes-per-bucket = 64)
#define BSZ 64                // nodes per bucket
#define MAXNB 3328            // LDS hist capacity; N <= 3328*64 = 212992
#define EB 512                // edge-chunk blocks for passes A/C
#define CTHR 512              // threads for passes A/C
#define SCAP 2560             // sort kernel LDS capacity (edges per bucket)

typedef unsigned uvec4 __attribute__((ext_vector_type(4)));
union U32H2 { unsigned u; __half2 h; };

__device__ __forceinline__ float tanh_fast(float x) {
    float e = __expf(2.0f * x);
    float r = __builtin_amdgcn_rcpf(1.0f + e);
    return 1.0f - 2.0f * r;
}

__device__ __forceinline__ float softplus_f(float x) {
    return fmaxf(x, 0.0f) + log1pf(expf(-fabsf(x)));
}

// ===================== prep =====================

__global__ __launch_bounds__(256) void coords4_kernel(
    const float* __restrict__ coords, float4* __restrict__ coords4, int N)
{
    int n = blockIdx.x * blockDim.x + threadIdx.x;
    if (n >= N) return;
    float4 c;
    c.x = coords[n * 3 + 0];
    c.y = coords[n * 3 + 1];
    c.z = coords[n * 3 + 2];
    c.w = 0.0f;
    coords4[n] = c;
}

// ===================== build: deterministic multi-split =====================

__global__ __launch_bounds__(CTHR) void bucket_count_kernel(
    const int* __restrict__ nto, unsigned* __restrict__ gcnt, int E, int NB)
{
    __shared__ unsigned h[MAXNB];
    int b = blockIdx.x;
    for (int i = threadIdx.x; i < NB; i += CTHR) h[i] = 0;
    __syncthreads();
    long long ebeg = (long long)E * b / EB;
    long long eend = (long long)E * (b + 1) / EB;
    for (long long e = ebeg + threadIdx.x; e < eend; e += CTHR)
        atomicAdd(&h[((unsigned)nto[e]) >> BB], 1u);
    __syncthreads();
    for (int k = threadIdx.x; k < NB; k += CTHR) gcnt[(size_t)k * EB + b] = h[k];
}

// Exclusive scan, level: 1024 items per 256-thread block. (no __restrict__: called in-place)
__global__ __launch_bounds__(256) void scan1_kernel(
    const unsigned* cnt, unsigned* off, unsigned* bsum, int M)
{
    __shared__ unsigned lds[256];
    int t = threadIdx.x, b = blockIdx.x;
    int base = b * 1024 + t * 4;
    unsigned v[4], s = 0;
#pragma unroll
    for (int k = 0; k < 4; k++) {
        v[k] = (base + k < M) ? cnt[base + k] : 0u;
        s += v[k];
    }
    lds[t] = s;
    __syncthreads();
    for (int d = 1; d < 256; d <<= 1) {
        unsigned x = (t >= d) ? lds[t - d] : 0u;
        __syncthreads();
        lds[t] += x;
        __syncthreads();
    }
    unsigned excl = (t > 0) ? lds[t - 1] : 0u;
    if (t == 255) bsum[b] = lds[255];
    unsigned run = excl;
#pragma unroll
    for (int k = 0; k < 4; k++) {
        if (base + k < M) off[base + k] = run;
        run += v[k];
    }
}

__global__ __launch_bounds__(256) void scan2_kernel(unsigned* __restrict__ bsum, int nb)
{
    __shared__ unsigned lds[256];
    int t = threadIdx.x;
    unsigned v = (t < nb) ? bsum[t] : 0u;
    lds[t] = v;
    __syncthreads();
    for (int d = 1; d < 256; d <<= 1) {
        unsigned x = (t >= d) ? lds[t - d] : 0u;
        __syncthreads();
        lds[t] += x;
        __syncthreads();
    }
    unsigned excl = (t > 0) ? lds[t - 1] : 0u;
    if (t < nb) bsum[t] = excl;
}

__global__ __launch_bounds__(256) void scan_add_kernel(
    unsigned* __restrict__ off, const unsigned* __restrict__ bsum, int M)
{
    int i = blockIdx.x * blockDim.x + threadIdx.x;
    if (i < M) off[i] += bsum[i >> 10];
}

__global__ __launch_bounds__(256) void bstart_kernel(
    const unsigned* __restrict__ gbase, unsigned* __restrict__ bstart, int NB, int E)
{
    int k = blockIdx.x * blockDim.x + threadIdx.x;
    if (k > NB) return;
    bstart[k] = (k < NB) ? gbase[(size_t)k * EB] : (unsigned)E;
}

// Pass C: emit bucket-sorted 16B payload {nf|lnt<<18, fp16 g0g1, fp16 g2g3, 0}
__global__ __launch_bounds__(CTHR) void bucket_scatter_kernel(
    const float4* __restrict__ coords4,
    const float* __restrict__ elen,
    const float* __restrict__ evec,
    const int* __restrict__ nfrom,
    const int* __restrict__ nto,
    const unsigned* __restrict__ gbase,
    uvec4* __restrict__ payload,
    int E, int NB)
{
    __shared__ unsigned cur[MAXNB];
    int b = blockIdx.x;
    for (int k = threadIdx.x; k < NB; k += CTHR) cur[k] = gbase[(size_t)k * EB + b];
    __syncthreads();
    long long ebeg = (long long)E * b / EB;
    long long eend = (long long)E * (b + 1) / EB;
    for (long long e = ebeg + threadIdx.x; e < eend; e += CTHR) {
        int nf = nfrom[e];
        int nt = nto[e];
        unsigned k = ((unsigned)nt) >> BB;
        unsigned pos = atomicAdd(&cur[k], 1u);

        float4 cf = coords4[nf];
        float4 ct = coords4[nt];
        float ev0 = evec[e * 3 + 0], ev1 = evec[e * 3 + 1], ev2 = evec[e * 3 + 2];

        float g0 = elen[e];
        float g1 = fabsf(cf.x) + fabsf(cf.y) + fabsf(cf.z);
        float g2 = cf.x * ct.x + cf.y * ct.y + cf.z * ct.z;
        float g3 = cf.x * ev0 + cf.y * ev1 + cf.z * ev2;

        U32H2 c01, c23;
        c01.h = __floats2half2_rn(g0, g1);
        c23.h = __floats2half2_rn(g2, g3);
        uvec4 p;
        p.x = (unsigned)nf | (((unsigned)nt & (BSZ - 1)) << 18);
        p.y = c01.u;
        p.z = c23.u;
        p.w = 0u;
        __builtin_nontemporal_store(p, &payload[pos]);
    }
}

// Pass D: per-bucket in-LDS counting sort by lnt (perf-only; oversized buckets skipped)
__global__ __launch_bounds__(256) void sort_bucket_kernel(
    const unsigned* __restrict__ bstart, uvec4* payload)
{
    __shared__ uvec4 sbuf[SCAP];           // 40 KB
    __shared__ unsigned scnt[BSZ], scur[BSZ];
    int k = blockIdx.x;
    unsigned beg = bstart[k], end = bstart[k + 1];
    unsigned len = end - beg;
    if (len > SCAP) return;                // leave unsorted (still correct)
    int t = threadIdx.x;
    if (t < BSZ) scnt[t] = 0;
    for (unsigned i = t; i < len; i += 256) sbuf[i] = payload[beg + i];
    __syncthreads();
    for (unsigned i = t; i < len; i += 256)
        atomicAdd(&scnt[(sbuf[i].x >> 18) & (BSZ - 1)], 1u);
    __syncthreads();
    if (t < 64) {
        unsigned v = scnt[t];
        unsigned inc = v;
        for (int d = 1; d < 64; d <<= 1) {
            unsigned u = __shfl_up(inc, d, 64);
            if (t >= d) inc += u;
        }
        scur[t] = inc - v;                 // exclusive prefix
    }
    __syncthreads();
    for (unsigned i = t; i < len; i += 256) {
        uvec4 p = sbuf[i];
        unsigned pos = atomicAdd(&scur[(p.x >> 18) & (BSZ - 1)], 1u);
        payload[beg + pos] = p;
    }
}

// ===================== rounds =====================

// wsth[n][j] = fp16( bm[j] + sum_k state[n][k] * Wm[k][j] ), dense 20B rows (4MB total)
__global__ __launch_bounds__(256) void wstate_kernel(
    const float* __restrict__ state, const float* __restrict__ Wm,
    const float* __restrict__ bm, __half* __restrict__ wsth, int N)
{
    int n = blockIdx.x * blockDim.x + threadIdx.x;
    if (n >= N) return;
    const float2* sp = (const float2*)(state + (size_t)n * SD);
    float s[SD];
#pragma unroll
    for (int h = 0; h < 5; h++) { float2 v = sp[h]; s[2*h] = v.x; s[2*h+1] = v.y; }
    float t[SD];
#pragma unroll
    for (int j = 0; j < SD; j++) t[j] = bm[j];
#pragma unroll
    for (int k = 0; k < SD; k++) {
#pragma unroll
        for (int j = 0; j < SD; j++) t[j] += s[k] * Wm[k * SD + j];
    }
    unsigned* dp = (unsigned*)(wsth + (size_t)n * SD);   // 20B rows, 4B aligned
#pragma unroll
    for (int h = 0; h < 5; h++) {
        U32H2 cv;
        cv.h = __floats2half2_rn(t[2*h], t[2*h+1]);
        dp[h] = cv.u;
    }
}

// Run-accumulating round kernel: 10 lanes/edge, 6 edges/wave-step; each wave owns a
// CONTIGUOUS quarter of its bucket's (destination-sorted) edges, so a group's lnt is
// constant over runs -> accumulate tanh in a register, LDS-atomic only on run change.
template <bool FIRST>
__global__ __launch_bounds__(256) void round_run_kernel(
    const unsigned* __restrict__ bstart,
    const uvec4* __restrict__ payload,
    const float* __restrict__ Wm,
    const float* __restrict__ bm,
    const __half* __restrict__ wsth,      // (N,10) dense fp16, incl bias
    const float* __restrict__ state_prev,
    float* __restrict__ state_next,
    int N, int E)
{
    __shared__ float acc[BSZ * SD];       // 2.56 KB
    int k = blockIdx.x;
    for (int i = threadIdx.x; i < BSZ * SD; i += 256) acc[i] = 0.0f;

    int lane = threadIdx.x & 63;
    int wv = threadIdx.x >> 6;            // 0..3
    int grp0 = lane / 10;
    bool active = grp0 < 6;
    int grp = active ? grp0 : 5;
    int j = active ? (lane - grp0 * 10) : (lane - 60);

    float w0 = Wm[10 * SD + j];
    float w1 = Wm[11 * SD + j];
    float w2 = Wm[12 * SD + j];
    float w3 = Wm[13 * SD + j];
    float bb = bm[j];
    __syncthreads();

    unsigned beg = bstart[k], end = bstart[k + 1];
    unsigned len = end - beg;
    unsigned Q = (len + 3) >> 2;
    unsigned rbeg = beg + (unsigned)wv * Q;
    unsigned rend = rbeg + Q; if (rend > end) rend = end;
    unsigned eclamp = (unsigned)E - 1u;

    // pipeline preload: payload depth 2, wst depth 1
    unsigned e0 = rbeg + (unsigned)grp;
    uvec4 P0 = __builtin_nontemporal_load(&payload[e0 <= eclamp ? e0 : eclamp]);
    unsigned e1 = e0 + 6;
    uvec4 P1 = __builtin_nontemporal_load(&payload[e1 <= eclamp ? e1 : eclamp]);
    float T0 = bb, T1 = bb;
    if (!FIRST) T0 = __half2float(wsth[(size_t)(P0.x & 0x3FFFFu) * SD + j]);

    int cur_lnt = -1;
    float accv = 0.0f;

    for (unsigned base = rbeg; base < rend; base += 6) {
        unsigned e2 = base + 12 + (unsigned)grp;
        uvec4 P2 = __builtin_nontemporal_load(&payload[e2 <= eclamp ? e2 : eclamp]);
        if (!FIRST) T1 = __half2float(wsth[(size_t)(P1.x & 0x3FFFFu) * SD + j]);
        unsigned e = base + (unsigned)grp;
        if (active && e < rend) {
            int lnt = (int)((P0.x >> 18) & (BSZ - 1));
            U32H2 c01, c23;
            c01.u = P0.y; c23.u = P0.z;
            float g0 = __low2float(c01.h), g1 = __high2float(c01.h);
            float g2 = __low2float(c23.h), g3 = __high2float(c23.h);
            float t = T0 + g0 * w0 + g1 * w1 + g2 * w2 + g3 * w3;
            if (lnt != cur_lnt) {
                if (cur_lnt >= 0) atomicAdd(&acc[cur_lnt * SD + j], accv);
                accv = 0.0f;
                cur_lnt = lnt;
            }
            accv += tanh_fast(t);
        }
        P0 = P1; P1 = P2; T0 = T1;
    }
    if (active && cur_lnt >= 0) atomicAdd(&acc[cur_lnt * SD + j], accv);
    __syncthreads();

    int base_o = k * BSZ * SD;
    int lim = N * SD - base_o;
    for (int i = threadIdx.x; i < BSZ * SD; i += 256) {
        if (i < lim) {
            float v = acc[i];
            if (!FIRST) v += state_prev[base_o + i];
            state_next[base_o + i] = v;
        }
    }
}

// ===================== graph phase =====================

__global__ __launch_bounds__(256) void goff_kernel(
    const int* __restrict__ gidx, unsigned* __restrict__ goff, int N, int G)
{
    int n = blockIdx.x * blockDim.x + threadIdx.x;
    if (n >= N) return;
    int g = gidx[n];
    if (n == 0) {
        for (int q = 0; q <= g; q++) goff[q] = 0;
    } else {
        int gp = gidx[n - 1];
        for (int q = gp + 1; q <= g; q++) goff[q] = (unsigned)n;
    }
    if (n == N - 1) {
        for (int q = g + 1; q <= G; q++) goff[q] = (unsigned)N;
    }
}

// 4-way split per (g,j); one atomic per partial. gstate must be zeroed.
__global__ __launch_bounds__(256) void gsum_kernel(
    const float* __restrict__ state, const unsigned* __restrict__ goff,
    float* __restrict__ gstate, int G)
{
    int tid = blockIdx.x * blockDim.x + threadIdx.x;
    if (tid >= G * SD * 4) return;
    int s = tid & 3;
    int rest = tid >> 2;
    int g = rest / SD;
    int j = rest - g * SD;
    unsigned beg = goff[g], end = goff[g + 1];
    unsigned len = end - beg;
    unsigned b0 = beg + (len * (unsigned)s) / 4u;
    unsigned b1 = beg + (len * (unsigned)(s + 1)) / 4u;
    float a = 0.0f;
    for (unsigned n = b0; n < b1; n++) a += state[(size_t)n * SD + j];
    atomicAdd(&gstate[(size_t)g * SD + j], a);
}

__global__ __launch_bounds__(256) void out_kernel(
    const float* __restrict__ gstate, const float* __restrict__ Wo,
    const float* __restrict__ bo, float* __restrict__ out, int G)
{
    int g = blockIdx.x * blockDim.x + threadIdx.x;
    if (g >= G) return;
    float s[SD];
#pragma unroll
    for (int k = 0; k < SD; k++) s[k] = gstate[(size_t)g * SD + k];
    float ev[4];
#pragma unroll
    for (int c = 0; c < 4; c++) {
        float a = bo[c];
#pragma unroll
        for (int k = 0; k < SD; k++) a += s[k] * Wo[k * 4 + c];
        ev[c] = a;
    }
    out[g * 4 + 0] = ev[0];
    out[g * 4 + 1] = softplus_f(ev[1]);
    out[g * 4 + 2] = softplus_f(ev[2]) + 1.0f;
    out[g * 4 + 3] = softplus_f(ev[3]);
}

// ===================== fallback (atomic path) =====================

template <bool FIRST>
__global__ __launch_bounds__(256) void edge_kernel_fb(
    const float* __restrict__ coords, const float* __restrict__ elen,
    const float* __restrict__ evec, const float* __restrict__ Wm,
    const float* __restrict__ bm, const int* __restrict__ nfrom,
    const int* __restrict__ nto, const float* __restrict__ state_prev,
    float* __restrict__ state_next, int E)
{
    int e = blockIdx.x * blockDim.x + threadIdx.x;
    if (e >= E) return;
    int nf = nfrom[e];
    int nt = nto[e];
    float cf0 = coords[nf*3+0], cf1 = coords[nf*3+1], cf2 = coords[nf*3+2];
    float ct0 = coords[nt*3+0], ct1 = coords[nt*3+1], ct2 = coords[nt*3+2];
    float ev0 = evec[e*3+0], ev1 = evec[e*3+1], ev2 = evec[e*3+2];
    float g0 = elen[e];
    float g1 = fabsf(cf0) + fabsf(cf1) + fabsf(cf2);
    float g2 = cf0*ct0 + cf1*ct1 + cf2*ct2;
    float g3 = cf0*ev0 + cf1*ev1 + cf2*ev2;
    float acc[SD];
#pragma unroll
    for (int j = 0; j < SD; j++) {
        acc[j] = bm[j] + g0*Wm[10*SD+j] + g1*Wm[11*SD+j] + g2*Wm[12*SD+j] + g3*Wm[13*SD+j];
    }
    if (!FIRST) {
        const float2* sp = (const float2*)(state_prev + (size_t)nf * SD);
        float s[SD];
#pragma unroll
        for (int h = 0; h < 5; h++) { float2 v = sp[h]; s[2*h] = v.x; s[2*h+1] = v.y; }
#pragma unroll
        for (int k = 0; k < SD; k++) {
#pragma unroll
            for (int j = 0; j < SD; j++) acc[j] += s[k] * Wm[k*SD+j];
        }
    }
    float* dst = state_next + (size_t)nt * SD;
#pragma unroll
    for (int j = 0; j < SD; j++) atomicAdd(dst + j, tanh_fast(acc[j]));
}

__global__ __launch_bounds__(256) void graph_reduce_fb(
    const float* __restrict__ state, const int* __restrict__ gidx,
    float* __restrict__ gstate, int N)
{
    int n = blockIdx.x * blockDim.x + threadIdx.x;
    if (n >= N) return;
    int g = gidx[n];
    const float2* sp = (const float2*)(state + (size_t)n * SD);
    float* dst = gstate + (size_t)g * SD;
#pragma unroll
    for (int h = 0; h < 5; h++) {
        float2 v = sp[h];
        atomicAdd(dst + 2*h, v.x);
        atomicAdd(dst + 2*h + 1, v.y);
    }
}

// ===================== launch =====================

extern "C" void kernel_launch(void* const* d_in, const int* in_sizes, int n_in,
                              void* d_out, int out_size, void* d_ws, size_t ws_size,
                              hipStream_t stream) {
    const float* coords = (const float*)d_in[0];
    const float* elen   = (const float*)d_in[1];
    const float* evec   = (const float*)d_in[2];
    const float* Wm     = (const float*)d_in[3];
    const float* bm     = (const float*)d_in[4];
    const float* Wo     = (const float*)d_in[5];
    const float* bo     = (const float*)d_in[6];
    const int* nfrom    = (const int*)d_in[7];
    const int* nto      = (const int*)d_in[8];
    const int* gidx     = (const int*)d_in[9];

    const int E = in_sizes[1];
    const int N = in_sizes[9];
    const int G = out_size / 4;

    const int NB  = (N + BSZ - 1) / BSZ;     // buckets
    const int M   = NB * EB;                 // scan length
    const int nb1 = (M + 1023) / 1024;       // scan level-1 blocks
    const int nb2 = (nb1 + 1023) / 1024;     // scan level-2 blocks

    const int BLK = 256;
    const int ng = (N + BLK - 1) / BLK;
    const int gg = (G + BLK - 1) / BLK;

    auto align256 = [](size_t x) { return (x + 255) & ~(size_t)255; };
    const size_t state_bytes = align256((size_t)N * SD * sizeof(float));
    const size_t wst_bytes   = align256((size_t)N * SD * sizeof(__half) + 256);
    const size_t pay_bytes   = align256((size_t)E * sizeof(uvec4));
    const size_t gcnt_bytes  = align256((size_t)M * sizeof(unsigned));
    const size_t bsumA_bytes = align256((size_t)nb1 * sizeof(unsigned));
    const size_t bsumB_bytes = align256((size_t)(nb2 > 0 ? nb2 : 1) * sizeof(unsigned) + 256);
    const size_t bst_bytes   = align256((size_t)(NB + 1) * sizeof(unsigned));
    const size_t goff_bytes  = align256((size_t)(G + 1) * sizeof(unsigned));
    const size_t gst_bytes   = align256((size_t)G * SD * sizeof(float));
    const size_t c4_bytes    = align256((size_t)N * sizeof(float4));

    size_t o = 0;
    char* w = (char*)d_ws;
    float* stateA    = (float*)(w + o);    o += state_bytes;
    float* stateB    = (float*)(w + o);    o += state_bytes;
    __half* wsth     = (__half*)(w + o);   o += wst_bytes;
    uvec4* payload   = (uvec4*)(w + o);    o += pay_bytes;
    unsigned* gcnt   = (unsigned*)(w + o); o += gcnt_bytes;
    unsigned* gbase  = (unsigned*)(w + o); o += gcnt_bytes;
    unsigned* bsumA  = (unsigned*)(w + o); o += bsumA_bytes;
    unsigned* bsumB  = (unsigned*)(w + o); o += bsumB_bytes;
    unsigned* bstart = (unsigned*)(w + o); o += bst_bytes;
    unsigned* goff   = (unsigned*)(w + o); o += goff_bytes;
    float* gstate    = (float*)(w + o);    o += gst_bytes;
    float4* coords4  = (float4*)(w + o);   o += c4_bytes;

    if (o <= ws_size && NB <= MAXNB && nb1 <= 1024 * 256 && nb2 <= 256 && N < (1 << 18)) {
        // ---- prep + build (no global atomics) ----
        coords4_kernel<<<ng, BLK, 0, stream>>>(coords, coords4, N);
        bucket_count_kernel<<<EB, CTHR, 0, stream>>>(nto, gcnt, E, NB);
        scan1_kernel<<<nb1, 256, 0, stream>>>(gcnt, gbase, bsumA, M);
        scan1_kernel<<<nb2, 256, 0, stream>>>(bsumA, bsumA, bsumB, nb1);   // in-place OK
        scan2_kernel<<<1, 256, 0, stream>>>(bsumB, nb2);
        scan_add_kernel<<<(nb1 + 255) / 256, 256, 0, stream>>>(bsumA, bsumB, nb1);
        scan_add_kernel<<<(M + 255) / 256, 256, 0, stream>>>(gbase, bsumA, M);
        bstart_kernel<<<(NB + 256) / 256, 256, 0, stream>>>(gbase, bstart, NB, E);
        bucket_scatter_kernel<<<EB, CTHR, 0, stream>>>(coords4, elen, evec, nfrom, nto,
                                                       gbase, payload, E, NB);
        sort_bucket_kernel<<<NB, BLK, 0, stream>>>(bstart, payload);
        // ---- rounds ----
        round_run_kernel<true><<<NB, BLK, 0, stream>>>(bstart, payload, Wm, bm,
                                                       wsth, stateB, stateA, N, E);
        wstate_kernel<<<ng, BLK, 0, stream>>>(stateA, Wm, bm, wsth, N);
        round_run_kernel<false><<<NB, BLK, 0, stream>>>(bstart, payload, Wm, bm,
                                                        wsth, stateA, stateB, N, E);
        wstate_kernel<<<ng, BLK, 0, stream>>>(stateB, Wm, bm, wsth, N);
        round_run_kernel<false><<<NB, BLK, 0, stream>>>(bstart, payload, Wm, bm,
                                                        wsth, stateB, stateA, N, E);
        // ---- graph phase ----
        hipMemsetAsync(gstate, 0, (size_t)G * SD * sizeof(float), stream);
        goff_kernel<<<ng, BLK, 0, stream>>>(gidx, goff, N, G);
        gsum_kernel<<<(G * SD * 4 + BLK - 1) / BLK, BLK, 0, stream>>>(stateA, goff, gstate, G);
        out_kernel<<<gg, BLK, 0, stream>>>(gstate, Wo, bo, (float*)d_out, G);
    } else {
        // ---- fallback: atomic path ----
        const int eg = (E + BLK - 1) / BLK;
        float* gstateF = (float*)(w + 2 * state_bytes);
        hipMemsetAsync(stateA, 0, state_bytes, stream);
        hipMemsetAsync(gstateF, 0, (size_t)G * SD * sizeof(float), stream);
        edge_kernel_fb<true><<<eg, BLK, 0, stream>>>(coords, elen, evec, Wm, bm,
                                                     nfrom, nto, stateA, stateA, E);
        hipMemcpyAsync(stateB, stateA, state_bytes, hipMemcpyDeviceToDevice, stream);
        edge_kernel_fb<false><<<eg, BLK, 0, stream>>>(coords, elen, evec, Wm, bm,
                                                      nfrom, nto, stateA, stateB, E);
        hipMemcpyAsync(stateA, stateB, state_bytes, hipMemcpyDeviceToDevice, stream);
        edge_kernel_fb<false><<<eg, BLK, 0, stream>>>(coords, elen, evec, Wm, bm,
                                                      nfrom, nto, stateB, stateA, E);
        graph_reduce_fb<<<ng, BLK, 0, stream>>>(stateA, gidx, gstateF, N);
        out_kernel<<<gg, BLK, 0, stream>>>(gstateF, Wo, bo, (float*)d_out, G);
    }
}

// Round 8
// 820.315 us; speedup vs baseline: 1.9940x; 1.1280x over previous
//
#include <hip/hip_runtime.h>
#include <hip/hip_fp16.h>
#include <math.h>

#define SD 10
#define BB 6                  // bucket bits (nodes-per-bucket = 64)
#define BSZ 64                // nodes per bucket
#define MAXNB 3328            // LDS hist capacity; N <= 3328*64 = 212992
#define EB 512                // edge-chunk blocks for passes A/C
#define CTHR 1024             // threads for passes A/C
#define SCAP 4096             // sort kernel LDS capacity (edges per bucket), 64KB

typedef unsigned uvec4 __attribute__((ext_vector_type(4)));
union U32H2 { unsigned u; __half2 h; };

__device__ __forceinline__ float tanh_fast(float x) {
    float e = __expf(2.0f * x);
    float r = __builtin_amdgcn_rcpf(1.0f + e);
    return 1.0f - 2.0f * r;
}

__device__ __forceinline__ float softplus_f(float x) {
    return fmaxf(x, 0.0f) + log1pf(expf(-fabsf(x)));
}

// ===================== prep =====================

__global__ __launch_bounds__(256) void coords4_kernel(
    const float* __restrict__ coords, float4* __restrict__ coords4, int N)
{
    int n = blockIdx.x * blockDim.x + threadIdx.x;
    if (n >= N) return;
    float4 c;
    c.x = coords[n * 3 + 0];
    c.y = coords[n * 3 + 1];
    c.z = coords[n * 3 + 2];
    c.w = 0.0f;
    coords4[n] = c;
}

// ===================== build: deterministic multi-split =====================

__global__ __launch_bounds__(CTHR) void bucket_count_kernel(
    const int* __restrict__ nto, unsigned* __restrict__ gcnt, int E, int NB)
{
    __shared__ unsigned h[MAXNB];
    int b = blockIdx.x;
    for (int i = threadIdx.x; i < NB; i += CTHR) h[i] = 0;
    __syncthreads();
    long long ebeg = (long long)E * b / EB;
    long long eend = (long long)E * (b + 1) / EB;
    for (long long e = ebeg + threadIdx.x; e < eend; e += CTHR)
        atomicAdd(&h[((unsigned)nto[e]) >> BB], 1u);
    __syncthreads();
    for (int k = threadIdx.x; k < NB; k += CTHR) gcnt[(size_t)k * EB + b] = h[k];
}

// Exclusive scan, level: 1024 items per 256-thread block. (no __restrict__: called in-place)
__global__ __launch_bounds__(256) void scan1_kernel(
    const unsigned* cnt, unsigned* off, unsigned* bsum, int M)
{
    __shared__ unsigned lds[256];
    int t = threadIdx.x, b = blockIdx.x;
    int base = b * 1024 + t * 4;
    unsigned v[4], s = 0;
#pragma unroll
    for (int k = 0; k < 4; k++) {
        v[k] = (base + k < M) ? cnt[base + k] : 0u;
        s += v[k];
    }
    lds[t] = s;
    __syncthreads();
    for (int d = 1; d < 256; d <<= 1) {
        unsigned x = (t >= d) ? lds[t - d] : 0u;
        __syncthreads();
        lds[t] += x;
        __syncthreads();
    }
    unsigned excl = (t > 0) ? lds[t - 1] : 0u;
    if (t == 255) bsum[b] = lds[255];
    unsigned run = excl;
#pragma unroll
    for (int k = 0; k < 4; k++) {
        if (base + k < M) off[base + k] = run;
        run += v[k];
    }
}

__global__ __launch_bounds__(256) void scan2_kernel(unsigned* __restrict__ bsum, int nb)
{
    __shared__ unsigned lds[256];
    int t = threadIdx.x;
    unsigned v = (t < nb) ? bsum[t] : 0u;
    lds[t] = v;
    __syncthreads();
    for (int d = 1; d < 256; d <<= 1) {
        unsigned x = (t >= d) ? lds[t - d] : 0u;
        __syncthreads();
        lds[t] += x;
        __syncthreads();
    }
    unsigned excl = (t > 0) ? lds[t - 1] : 0u;
    if (t < nb) bsum[t] = excl;
}

__global__ __launch_bounds__(256) void scan_add_kernel(
    unsigned* __restrict__ off, const unsigned* __restrict__ bsum, int M)
{
    int i = blockIdx.x * blockDim.x + threadIdx.x;
    if (i < M) off[i] += bsum[i >> 10];
}

__global__ __launch_bounds__(256) void bstart_kernel(
    const unsigned* __restrict__ gbase, unsigned* __restrict__ bstart, int NB, int E)
{
    int k = blockIdx.x * blockDim.x + threadIdx.x;
    if (k > NB) return;
    bstart[k] = (k < NB) ? gbase[(size_t)k * EB] : (unsigned)E;
}

// Pass C: emit bucket-sorted 16B payload {nf|lnt<<18, fp16 g0g1, fp16 g2g3, 0}
// Regular (cached) stores: L2 write-combines the contiguous per-(block,bucket) cells.
__global__ __launch_bounds__(CTHR) void bucket_scatter_kernel(
    const float4* __restrict__ coords4,
    const float* __restrict__ elen,
    const float* __restrict__ evec,
    const int* __restrict__ nfrom,
    const int* __restrict__ nto,
    const unsigned* __restrict__ gbase,
    uvec4* __restrict__ payload,
    int E, int NB)
{
    __shared__ unsigned cur[MAXNB];
    int b = blockIdx.x;
    for (int k = threadIdx.x; k < NB; k += CTHR) cur[k] = gbase[(size_t)k * EB + b];
    __syncthreads();
    long long ebeg = (long long)E * b / EB;
    long long eend = (long long)E * (b + 1) / EB;
    for (long long e = ebeg + threadIdx.x; e < eend; e += CTHR) {
        int nf = nfrom[e];
        int nt = nto[e];
        unsigned k = ((unsigned)nt) >> BB;
        unsigned pos = atomicAdd(&cur[k], 1u);

        float4 cf = coords4[nf];
        float4 ct = coords4[nt];
        float ev0 = evec[e * 3 + 0], ev1 = evec[e * 3 + 1], ev2 = evec[e * 3 + 2];

        float g0 = elen[e];
        float g1 = fabsf(cf.x) + fabsf(cf.y) + fabsf(cf.z);
        float g2 = cf.x * ct.x + cf.y * ct.y + cf.z * ct.z;
        float g3 = cf.x * ev0 + cf.y * ev1 + cf.z * ev2;

        U32H2 c01, c23;
        c01.h = __floats2half2_rn(g0, g1);
        c23.h = __floats2half2_rn(g2, g3);
        uvec4 p;
        p.x = (unsigned)nf | (((unsigned)nt & (BSZ - 1)) << 18);
        p.y = c01.u;
        p.z = c23.u;
        p.w = 0u;
        payload[pos] = p;
    }
}

// Pass D: per-bucket in-LDS counting sort by lnt (perf-only; oversized buckets skipped)
__global__ __launch_bounds__(256) void sort_bucket_kernel(
    const unsigned* __restrict__ bstart, uvec4* payload)
{
    __shared__ uvec4 sbuf[SCAP];           // 64 KB
    __shared__ unsigned scnt[BSZ], scur[BSZ];
    int k = blockIdx.x;
    unsigned beg = bstart[k], end = bstart[k + 1];
    unsigned len = end - beg;
    if (len > SCAP) return;                // leave unsorted (still correct)
    int t = threadIdx.x;
    if (t < BSZ) scnt[t] = 0;
    for (unsigned i = t; i < len; i += 256) sbuf[i] = payload[beg + i];
    __syncthreads();
    for (unsigned i = t; i < len; i += 256)
        atomicAdd(&scnt[(sbuf[i].x >> 18) & (BSZ - 1)], 1u);
    __syncthreads();
    if (t < 64) {
        unsigned v = scnt[t];
        unsigned inc = v;
        for (int d = 1; d < 64; d <<= 1) {
            unsigned u = __shfl_up(inc, d, 64);
            if (t >= d) inc += u;
        }
        scur[t] = inc - v;                 // exclusive prefix
    }
    __syncthreads();
    for (unsigned i = t; i < len; i += 256) {
        uvec4 p = sbuf[i];
        unsigned pos = atomicAdd(&scur[(p.x >> 18) & (BSZ - 1)], 1u);
        payload[beg + pos] = p;
    }
}

// ===================== rounds =====================

// wsth[n][j] = fp16( bm[j] + sum_k state[n][k] * Wm[k][j] ), dense 20B rows (4MB total)
__global__ __launch_bounds__(256) void wstate_kernel(
    const float* __restrict__ state, const float* __restrict__ Wm,
    const float* __restrict__ bm, __half* __restrict__ wsth, int N)
{
    int n = blockIdx.x * blockDim.x + threadIdx.x;
    if (n >= N) return;
    const float2* sp = (const float2*)(state + (size_t)n * SD);
    float s[SD];
#pragma unroll
    for (int h = 0; h < 5; h++) { float2 v = sp[h]; s[2*h] = v.x; s[2*h+1] = v.y; }
    float t[SD];
#pragma unroll
    for (int j = 0; j < SD; j++) t[j] = bm[j];
#pragma unroll
    for (int k = 0; k < SD; k++) {
#pragma unroll
        for (int j = 0; j < SD; j++) t[j] += s[k] * Wm[k * SD + j];
    }
    unsigned* dp = (unsigned*)(wsth + (size_t)n * SD);   // 20B rows, 4B aligned
#pragma unroll
    for (int h = 0; h < 5; h++) {
        U32H2 cv;
        cv.h = __floats2half2_rn(t[2*h], t[2*h+1]);
        dp[h] = cv.u;
    }
}

// Run-accumulating round kernel: 10 lanes/edge, 6 edges/wave-step; each wave owns a
// CONTIGUOUS quarter of its bucket's (destination-sorted) edges, so a group's lnt is
// constant over runs -> accumulate tanh in a register, LDS-atomic only on run change.
// Cached payload loads: 102 MB payload stays LLC-resident across sort + 3 rounds.
template <bool FIRST>
__global__ __launch_bounds__(256) void round_run_kernel(
    const unsigned* __restrict__ bstart,
    const uvec4* __restrict__ payload,
    const float* __restrict__ Wm,
    const float* __restrict__ bm,
    const __half* __restrict__ wsth,      // (N,10) dense fp16, incl bias
    const float* __restrict__ state_prev,
    float* __restrict__ state_next,
    int N, int E)
{
    __shared__ float acc[BSZ * SD];       // 2.56 KB
    int k = blockIdx.x;
    for (int i = threadIdx.x; i < BSZ * SD; i += 256) acc[i] = 0.0f;

    int lane = threadIdx.x & 63;
    int wv = threadIdx.x >> 6;            // 0..3
    int grp0 = lane / 10;
    bool active = grp0 < 6;
    int grp = active ? grp0 : 5;
    int j = active ? (lane - grp0 * 10) : (lane - 60);

    float w0 = Wm[10 * SD + j];
    float w1 = Wm[11 * SD + j];
    float w2 = Wm[12 * SD + j];
    float w3 = Wm[13 * SD + j];
    float bb = bm[j];
    __syncthreads();

    unsigned beg = bstart[k], end = bstart[k + 1];
    unsigned len = end - beg;
    unsigned Q = (len + 3) >> 2;
    unsigned rbeg = beg + (unsigned)wv * Q;
    unsigned rend = rbeg + Q; if (rend > end) rend = end;
    unsigned eclamp = (unsigned)E - 1u;

    // pipeline preload: payload depth 2, wst depth 1
    unsigned e0 = rbeg + (unsigned)grp;
    uvec4 P0 = payload[e0 <= eclamp ? e0 : eclamp];
    unsigned e1 = e0 + 6;
    uvec4 P1 = payload[e1 <= eclamp ? e1 : eclamp];
    float T0 = bb, T1 = bb;
    if (!FIRST) T0 = __half2float(wsth[(size_t)(P0.x & 0x3FFFFu) * SD + j]);

    int cur_lnt = -1;
    float accv = 0.0f;

    for (unsigned base = rbeg; base < rend; base += 6) {
        unsigned e2 = base + 12 + (unsigned)grp;
        uvec4 P2 = payload[e2 <= eclamp ? e2 : eclamp];
        if (!FIRST) T1 = __half2float(wsth[(size_t)(P1.x & 0x3FFFFu) * SD + j]);
        unsigned e = base + (unsigned)grp;
        if (active && e < rend) {
            int lnt = (int)((P0.x >> 18) & (BSZ - 1));
            U32H2 c01, c23;
            c01.u = P0.y; c23.u = P0.z;
            float g0 = __low2float(c01.h), g1 = __high2float(c01.h);
            float g2 = __low2float(c23.h), g3 = __high2float(c23.h);
            float t = T0 + g0 * w0 + g1 * w1 + g2 * w2 + g3 * w3;
            if (lnt != cur_lnt) {
                if (cur_lnt >= 0) atomicAdd(&acc[cur_lnt * SD + j], accv);
                accv = 0.0f;
                cur_lnt = lnt;
            }
            accv += tanh_fast(t);
        }
        P0 = P1; P1 = P2; T0 = T1;
    }
    if (active && cur_lnt >= 0) atomicAdd(&acc[cur_lnt * SD + j], accv);
    __syncthreads();

    int base_o = k * BSZ * SD;
    int lim = N * SD - base_o;
    for (int i = threadIdx.x; i < BSZ * SD; i += 256) {
        if (i < lim) {
            float v = acc[i];
            if (!FIRST) v += state_prev[base_o + i];
            state_next[base_o + i] = v;
        }
    }
}

// ===================== graph phase =====================

__global__ __launch_bounds__(256) void goff_kernel(
    const int* __restrict__ gidx, unsigned* __restrict__ goff, int N, int G)
{
    int n = blockIdx.x * blockDim.x + threadIdx.x;
    if (n >= N) return;
    int g = gidx[n];
    if (n == 0) {
        for (int q = 0; q <= g; q++) goff[q] = 0;
    } else {
        int gp = gidx[n - 1];
        for (int q = gp + 1; q <= g; q++) goff[q] = (unsigned)n;
    }
    if (n == N - 1) {
        for (int q = g + 1; q <= G; q++) goff[q] = (unsigned)N;
    }
}

// 4-way split per (g,j); one atomic per partial. gstate must be zeroed.
__global__ __launch_bounds__(256) void gsum_kernel(
    const float* __restrict__ state, const unsigned* __restrict__ goff,
    float* __restrict__ gstate, int G)
{
    int tid = blockIdx.x * blockDim.x + threadIdx.x;
    if (tid >= G * SD * 4) return;
    int s = tid & 3;
    int rest = tid >> 2;
    int g = rest / SD;
    int j = rest - g * SD;
    unsigned beg = goff[g], end = goff[g + 1];
    unsigned len = end - beg;
    unsigned b0 = beg + (len * (unsigned)s) / 4u;
    unsigned b1 = beg + (len * (unsigned)(s + 1)) / 4u;
    float a = 0.0f;
    for (unsigned n = b0; n < b1; n++) a += state[(size_t)n * SD + j];
    atomicAdd(&gstate[(size_t)g * SD + j], a);
}

__global__ __launch_bounds__(256) void out_kernel(
    const float* __restrict__ gstate, const float* __restrict__ Wo,
    const float* __restrict__ bo, float* __restrict__ out, int G)
{
    int g = blockIdx.x * blockDim.x + threadIdx.x;
    if (g >= G) return;
    float s[SD];
#pragma unroll
    for (int k = 0; k < SD; k++) s[k] = gstate[(size_t)g * SD + k];
    float ev[4];
#pragma unroll
    for (int c = 0; c < 4; c++) {
        float a = bo[c];
#pragma unroll
        for (int k = 0; k < SD; k++) a += s[k] * Wo[k * 4 + c];
        ev[c] = a;
    }
    out[g * 4 + 0] = ev[0];
    out[g * 4 + 1] = softplus_f(ev[1]);
    out[g * 4 + 2] = softplus_f(ev[2]) + 1.0f;
    out[g * 4 + 3] = softplus_f(ev[3]);
}

// ===================== fallback (atomic path) =====================

template <bool FIRST>
__global__ __launch_bounds__(256) void edge_kernel_fb(
    const float* __restrict__ coords, const float* __restrict__ elen,
    const float* __restrict__ evec, const float* __restrict__ Wm,
    const float* __restrict__ bm, const int* __restrict__ nfrom,
    const int* __restrict__ nto, const float* __restrict__ state_prev,
    float* __restrict__ state_next, int E)
{
    int e = blockIdx.x * blockDim.x + threadIdx.x;
    if (e >= E) return;
    int nf = nfrom[e];
    int nt = nto[e];
    float cf0 = coords[nf*3+0], cf1 = coords[nf*3+1], cf2 = coords[nf*3+2];
    float ct0 = coords[nt*3+0], ct1 = coords[nt*3+1], ct2 = coords[nt*3+2];
    float ev0 = evec[e*3+0], ev1 = evec[e*3+1], ev2 = evec[e*3+2];
    float g0 = elen[e];
    float g1 = fabsf(cf0) + fabsf(cf1) + fabsf(cf2);
    float g2 = cf0*ct0 + cf1*ct1 + cf2*ct2;
    float g3 = cf0*ev0 + cf1*ev1 + cf2*ev2;
    float acc[SD];
#pragma unroll
    for (int j = 0; j < SD; j++) {
        acc[j] = bm[j] + g0*Wm[10*SD+j] + g1*Wm[11*SD+j] + g2*Wm[12*SD+j] + g3*Wm[13*SD+j];
    }
    if (!FIRST) {
        const float2* sp = (const float2*)(state_prev + (size_t)nf * SD);
        float s[SD];
#pragma unroll
        for (int h = 0; h < 5; h++) { float2 v = sp[h]; s[2*h] = v.x; s[2*h+1] = v.y; }
#pragma unroll
        for (int k = 0; k < SD; k++) {
#pragma unroll
            for (int j = 0; j < SD; j++) acc[j] += s[k] * Wm[k*SD+j];
        }
    }
    float* dst = state_next + (size_t)nt * SD;
#pragma unroll
    for (int j = 0; j < SD; j++) atomicAdd(dst + j, tanh_fast(acc[j]));
}

__global__ __launch_bounds__(256) void graph_reduce_fb(
    const float* __restrict__ state, const int* __restrict__ gidx,
    float* __restrict__ gstate, int N)
{
    int n = blockIdx.x * blockDim.x + threadIdx.x;
    if (n >= N) return;
    int g = gidx[n];
    const float2* sp = (const float2*)(state + (size_t)n * SD);
    float* dst = gstate + (size_t)g * SD;
#pragma unroll
    for (int h = 0; h < 5; h++) {
        float2 v = sp[h];
        atomicAdd(dst + 2*h, v.x);
        atomicAdd(dst + 2*h + 1, v.y);
    }
}

// ===================== launch =====================

extern "C" void kernel_launch(void* const* d_in, const int* in_sizes, int n_in,
                              void* d_out, int out_size, void* d_ws, size_t ws_size,
                              hipStream_t stream) {
    const float* coords = (const float*)d_in[0];
    const float* elen   = (const float*)d_in[1];
    const float* evec   = (const float*)d_in[2];
    const float* Wm     = (const float*)d_in[3];
    const float* bm     = (const float*)d_in[4];
    const float* Wo     = (const float*)d_in[5];
    const float* bo     = (const float*)d_in[6];
    const int* nfrom    = (const int*)d_in[7];
    const int* nto      = (const int*)d_in[8];
    const int* gidx     = (const int*)d_in[9];

    const int E = in_sizes[1];
    const int N = in_sizes[9];
    const int G = out_size / 4;

    const int NB  = (N + BSZ - 1) / BSZ;     // buckets
    const int M   = NB * EB;                 // scan length
    const int nb1 = (M + 1023) / 1024;       // scan level-1 blocks
    const int nb2 = (nb1 + 1023) / 1024;     // scan level-2 blocks

    const int BLK = 256;
    const int ng = (N + BLK - 1) / BLK;
    const int gg = (G + BLK - 1) / BLK;

    auto align256 = [](size_t x) { return (x + 255) & ~(size_t)255; };
    const size_t state_bytes = align256((size_t)N * SD * sizeof(float));
    const size_t wst_bytes   = align256((size_t)N * SD * sizeof(__half) + 256);
    const size_t pay_bytes   = align256((size_t)E * sizeof(uvec4));
    const size_t gcnt_bytes  = align256((size_t)M * sizeof(unsigned));
    const size_t bsumA_bytes = align256((size_t)nb1 * sizeof(unsigned));
    const size_t bsumB_bytes = align256((size_t)(nb2 > 0 ? nb2 : 1) * sizeof(unsigned) + 256);
    const size_t bst_bytes   = align256((size_t)(NB + 1) * sizeof(unsigned));
    const size_t goff_bytes  = align256((size_t)(G + 1) * sizeof(unsigned));
    const size_t gst_bytes   = align256((size_t)G * SD * sizeof(float));
    const size_t c4_bytes    = align256((size_t)N * sizeof(float4));

    size_t o = 0;
    char* w = (char*)d_ws;
    float* stateA    = (float*)(w + o);    o += state_bytes;
    float* stateB    = (float*)(w + o);    o += state_bytes;
    __half* wsth     = (__half*)(w + o);   o += wst_bytes;
    uvec4* payload   = (uvec4*)(w + o);    o += pay_bytes;
    unsigned* gcnt   = (unsigned*)(w + o); o += gcnt_bytes;
    unsigned* gbase  = (unsigned*)(w + o); o += gcnt_bytes;
    unsigned* bsumA  = (unsigned*)(w + o); o += bsumA_bytes;
    unsigned* bsumB  = (unsigned*)(w + o); o += bsumB_bytes;
    unsigned* bstart = (unsigned*)(w + o); o += bst_bytes;
    unsigned* goff   = (unsigned*)(w + o); o += goff_bytes;
    float* gstate    = (float*)(w + o);    o += gst_bytes;
    float4* coords4  = (float4*)(w + o);   o += c4_bytes;

    if (o <= ws_size && NB <= MAXNB && nb1 <= 1024 * 256 && nb2 <= 256 && N < (1 << 18)) {
        // ---- prep + build (no global atomics) ----
        coords4_kernel<<<ng, BLK, 0, stream>>>(coords, coords4, N);
        bucket_count_kernel<<<EB, CTHR, 0, stream>>>(nto, gcnt, E, NB);
        scan1_kernel<<<nb1, 256, 0, stream>>>(gcnt, gbase, bsumA, M);
        scan1_kernel<<<nb2, 256, 0, stream>>>(bsumA, bsumA, bsumB, nb1);   // in-place OK
        scan2_kernel<<<1, 256, 0, stream>>>(bsumB, nb2);
        scan_add_kernel<<<(nb1 + 255) / 256, 256, 0, stream>>>(bsumA, bsumB, nb1);
        scan_add_kernel<<<(M + 255) / 256, 256, 0, stream>>>(gbase, bsumA, M);
        bstart_kernel<<<(NB + 256) / 256, 256, 0, stream>>>(gbase, bstart, NB, E);
        bucket_scatter_kernel<<<EB, CTHR, 0, stream>>>(coords4, elen, evec, nfrom, nto,
                                                       gbase, payload, E, NB);
        sort_bucket_kernel<<<NB, BLK, 0, stream>>>(bstart, payload);
        // ---- rounds ----
        round_run_kernel<true><<<NB, BLK, 0, stream>>>(bstart, payload, Wm, bm,
                                                       wsth, stateB, stateA, N, E);
        wstate_kernel<<<ng, BLK, 0, stream>>>(stateA, Wm, bm, wsth, N);
        round_run_kernel<false><<<NB, BLK, 0, stream>>>(bstart, payload, Wm, bm,
                                                        wsth, stateA, stateB, N, E);
        wstate_kernel<<<ng, BLK, 0, stream>>>(stateB, Wm, bm, wsth, N);
        round_run_kernel<false><<<NB, BLK, 0, stream>>>(bstart, payload, Wm, bm,
                                                        wsth, stateB, stateA, N, E);
        // ---- graph phase ----
        hipMemsetAsync(gstate, 0, (size_t)G * SD * sizeof(float), stream);
        goff_kernel<<<ng, BLK, 0, stream>>>(gidx, goff, N, G);
        gsum_kernel<<<(G * SD * 4 + BLK - 1) / BLK, BLK, 0, stream>>>(stateA, goff, gstate, G);
        out_kernel<<<gg, BLK, 0, stream>>>(gstate, Wo, bo, (float*)d_out, G);
    } else {
        // ---- fallback: atomic path ----
        const int eg = (E + BLK - 1) / BLK;
        float* gstateF = (float*)(w + 2 * state_bytes);
        hipMemsetAsync(stateA, 0, state_bytes, stream);
        hipMemsetAsync(gstateF, 0, (size_t)G * SD * sizeof(float), stream);
        edge_kernel_fb<true><<<eg, BLK, 0, stream>>>(coords, elen, evec, Wm, bm,
                                                     nfrom, nto, stateA, stateA, E);
        hipMemcpyAsync(stateB, stateA, state_bytes, hipMemcpyDeviceToDevice, stream);
        edge_kernel_fb<false><<<eg, BLK, 0, stream>>>(coords, elen, evec, Wm, bm,
                                                      nfrom, nto, stateA, stateB, E);
        hipMemcpyAsync(stateA, stateB, state_bytes, hipMemcpyDeviceToDevice, stream);
        edge_kernel_fb<false><<<eg, BLK, 0, stream>>>(coords, elen, evec, Wm, bm,
                                                      nfrom, nto, stateB, stateA, E);
        graph_reduce_fb<<<ng, BLK, 0, stream>>>(stateA, gidx, gstateF, N);
        out_kernel<<<gg, BLK, 0, stream>>>(gstateF, Wo, bo, (float*)d_out, G);
    }
}